// Round 7
// baseline (233.945 us; speedup 1.0000x reference)
//
#include <hip/hip_runtime.h>
#include <math.h>

// OscillatoryAttention: B=2,S=2048,D=1024,H=16,dk=64. FP32 in/out, bf16 MFMA inside.
// R13: revert GEMMs to baseline m97 BK=32 2-barrier (R12's BK=64 single-buffer was -15us).
//      prep phase GEMV vectorized: reuse the float4 x load, 16 coalesced float4 Wp
//      loads/thread (VMEM instr 128 -> 17/thread), padded [256][17] LDS reduce.
//      attn = R9 (58us plateau). Accumulation order in GEMMs unchanged.

#define S_LEN 2048
#define NHEADS 16

typedef __attribute__((ext_vector_type(8))) short short8;
typedef __attribute__((ext_vector_type(4))) float floatx4;
typedef __attribute__((ext_vector_type(2))) float float2v;
typedef __attribute__((ext_vector_type(4))) unsigned int uintx4;

__device__ inline unsigned short f2bf(float f) {
    union { float f; unsigned int i; } v; v.f = f;
    unsigned int u = v.i;
    return (unsigned short)((u + 0x7fffu + ((u >> 16) & 1u)) >> 16);
}
// pack two f32 -> packed bf16 u32 (truncation), low short = lo
__device__ inline unsigned int pack2_bf16(float hi, float lo) {
    union { float f; unsigned int u; } a, b; a.f = hi; b.f = lo;
    return __builtin_amdgcn_perm(a.u, b.u, 0x07060302u);
}
__device__ inline void async_copy16(const unsigned short* src, unsigned short* dst_lds) {
    __builtin_amdgcn_global_load_lds(
        (const __attribute__((address_space(1))) unsigned int*)(src),
        (__attribute__((address_space(3))) unsigned int*)(dst_lds), 16, 0, 0);
}
__device__ inline void async_copy4(const float* src, float* dst_lds) {
    __builtin_amdgcn_global_load_lds(
        (const __attribute__((address_space(1))) unsigned int*)(src),
        (__attribute__((address_space(3))) unsigned int*)(dst_lds), 4, 0, 0);
}

// ---------------- prep: phase+cvt (blocks 0..4095) | weight transpose (4096..5119)
// Phase branch: xv (float4 of x) feeds BOTH the bf16 convert and the Wp GEMV.
// Thread t owns k-rows 4t..4t+3: 16 float4 Wp loads (wave = 16KB contiguous),
// 64 FMA into facc[16]; two-stage reduce in padded LDS [256][17] (conflict-free).
__global__ __launch_bounds__(256) void prep_kernel(
    const float* __restrict__ x, const float* __restrict__ Wp,
    const float* __restrict__ bp,
    const float* __restrict__ w0, const float* __restrict__ w1,
    const float* __restrict__ w2, const float* __restrict__ w3,
    unsigned short* __restrict__ d0, unsigned short* __restrict__ d1,
    unsigned short* __restrict__ d2, unsigned short* __restrict__ d3,
    float* __restrict__ cosP, float* __restrict__ sinP,
    unsigned short* __restrict__ xb) {
    __shared__ __align__(16) unsigned short shmem[8704];   // 17408 B union
    int t = threadIdx.x;
    if (blockIdx.x < 4096) {
        float (*red)[17] = reinterpret_cast<float (*)[17]>(shmem);
        int bid = blockIdx.x;
        int b = bid >> 11, s = bid & 2047;
        const float* xr = x + (size_t)bid * 1024;
        float4 xv = *reinterpret_cast<const float4*>(&xr[t * 4]);
        {
            uint2 o;
            o.x = (unsigned int)f2bf(xv.x) | ((unsigned int)f2bf(xv.y) << 16);
            o.y = (unsigned int)f2bf(xv.z) | ((unsigned int)f2bf(xv.w) << 16);
            *reinterpret_cast<uint2*>(&xb[(size_t)bid * 1024 + t * 4]) = o;
        }
        // GEMV partials for all 16 heads from this thread's 4 k-rows
        float facc[16];
#pragma unroll
        for (int h = 0; h < 16; h++) facc[h] = 0.f;
        const float* wr = Wp + (size_t)t * 64;      // rows 4t..4t+3 of Wp (16 f32 each)
#pragma unroll
        for (int j = 0; j < 4; j++) {
            float xj = (j == 0) ? xv.x : (j == 1) ? xv.y : (j == 2) ? xv.z : xv.w;
#pragma unroll
            for (int q = 0; q < 4; q++) {
                float4 wv = *reinterpret_cast<const float4*>(&wr[j * 16 + q * 4]);
                facc[q * 4 + 0] += xj * wv.x;
                facc[q * 4 + 1] += xj * wv.y;
                facc[q * 4 + 2] += xj * wv.z;
                facc[q * 4 + 3] += xj * wv.w;
            }
        }
#pragma unroll
        for (int h = 0; h < 16; h++) red[t][h] = facc[h];
        __syncthreads();
        // stage A: thread t sums 16 partial rows for head (t&15), group (t>>4)
        int h = t & 15, g0 = (t >> 4) * 16;
        float sA = 0.f;
#pragma unroll
        for (int i = 0; i < 16; i++) sA += red[g0 + i][h];
        __syncthreads();
        red[t >> 4][h] = sA;        // (t>>4, t&15) unique -> rows 0..15
        __syncthreads();
        if (t < 16) {
            float sum = bp[t];
#pragma unroll
            for (int g = 0; g < 16; g++) sum += red[g][t];
            float sv, cv;
            __sincosf(sum, &sv, &cv);
            size_t o = ((size_t)b * NHEADS + t) * S_LEN + s;
            cosP[o] = cv; sinP[o] = sv;
        }
    } else {
        unsigned short (*tile)[72] = reinterpret_cast<unsigned short (*)[72]>(shmem);
        int bid = blockIdx.x - 4096;
        int mat = bid >> 8;
        int tl  = bid & 255;
        int tr = tl >> 4, tc = tl & 15;
        const float* src    = (mat == 0) ? w0 : (mat == 1) ? w1 : (mat == 2) ? w2 : w3;
        unsigned short* dst = (mat == 0) ? d0 : (mat == 1) ? d1 : (mat == 2) ? d2 : d3;
        int col = t & 63, rbase = (t >> 6) * 16;
#pragma unroll
        for (int i = 0; i < 16; i++) {
            int row = rbase + i;
            tile[row][col] = f2bf(src[(size_t)(tr * 64 + row) * 1024 + tc * 64 + col]);
        }
        __syncthreads();
#pragma unroll
        for (int i = 0; i < 16; i++) {
            int row = rbase + i;
            dst[(size_t)(tc * 64 + row) * 1024 + tr * 64 + col] = tile[col][row];
        }
    }
}

// ---------------- GEMM (m97 recipe, baseline BK=32) ------------------------------
// mode 0: row-major fp32 out (+bias) -> of
// mode 1: N=3072 QKV: Q scaled 0.125*log2e -> (B,H,S,dk); K -> (B,H,S,dk);
//         V -> (B,H,dk,S) transposed AND pi-interleaved within 64-token chunks:
//         token j=32a+16c+b lands at short u=32a+2b+c.
template <int MT>
__global__ __launch_bounds__(256) void gemm_bt(
    const unsigned short* __restrict__ A, const unsigned short* __restrict__ BT,
    int N, int mode,
    const float* __restrict__ b0, const float* __restrict__ b1,
    const float* __restrict__ b2,
    unsigned short* __restrict__ o0, unsigned short* __restrict__ o1,
    unsigned short* __restrict__ o2, float* __restrict__ of) {
    __shared__ __align__(16) unsigned short As[MT * 32];
    __shared__ __align__(16) unsigned short Bs[128 * 32];
    const int K = 1024;
    const int MI = MT / 32;
    int t = threadIdx.x;
    int mBase = blockIdx.x * MT;
    int nBase = blockIdx.y * 128;
    int w = t >> 6, lane = t & 63, l15 = lane & 15, quad = lane >> 4;
    int wm = (w & 1) * (MT / 2), wn = (w >> 1) * 64;
    floatx4 acc[MI][4];
#pragma unroll
    for (int i = 0; i < MI; i++)
#pragma unroll
        for (int j = 0; j < 4; j++) acc[i][j] = (floatx4){0.f, 0.f, 0.f, 0.f};

    int arow = t >> 2, aseg = (t & 3) * 8;
    for (int k0 = 0; k0 < K; k0 += 32) {
        __syncthreads();
#pragma unroll
        for (int i = 0; i < MT / 64; i++)
            async_copy16(&A[(size_t)(mBase + i * 64 + arow) * K + k0 + aseg],
                         &As[(i * 64 + arow) * 32 + aseg]);
#pragma unroll
        for (int i = 0; i < 2; i++)
            async_copy16(&BT[(size_t)(nBase + i * 64 + arow) * K + k0 + aseg],
                         &Bs[(i * 64 + arow) * 32 + aseg]);
        __syncthreads();
        short8 af[MI], bfr[4];
#pragma unroll
        for (int mi = 0; mi < MI; mi++)
            af[mi] = *reinterpret_cast<const short8*>(&As[(wm + mi * 16 + l15) * 32 + quad * 8]);
#pragma unroll
        for (int ni = 0; ni < 4; ni++)
            bfr[ni] = *reinterpret_cast<const short8*>(&Bs[(wn + ni * 16 + l15) * 32 + quad * 8]);
#pragma unroll
        for (int mi = 0; mi < MI; mi++)
#pragma unroll
            for (int ni = 0; ni < 4; ni++)
                acc[mi][ni] = __builtin_amdgcn_mfma_f32_16x16x32_bf16(af[mi], bfr[ni], acc[mi][ni], 0, 0, 0);
    }

#pragma unroll
    for (int mi = 0; mi < MI; mi++) {
        int rowB = mBase + wm + mi * 16 + quad * 4;
#pragma unroll
        for (int ni = 0; ni < 4; ni++) {
            int col = nBase + wn + ni * 16 + l15;
            if (mode == 0) {
                float bias = b0[col];
#pragma unroll
                for (int r = 0; r < 4; r++) {
                    of[(size_t)(rowB + r) * N + col] = acc[mi][ni][r] + bias;
                }
            } else {
                int mat = col >> 10, nn = col & 1023;
                int h = nn >> 6, d = nn & 63;
                int b = rowB >> 11, sidx = rowB & 2047;
                if (mat == 2) {
                    float bv = b2[nn];
                    int jj = sidx & 63;                 // multiple of 4
                    int a2 = jj >> 5, c2 = (jj >> 4) & 1, bb = jj & 15;
                    size_t rowOff = ((size_t)((b * NHEADS + h) * 64 + d)) * S_LEN +
                                    (sidx & ~63) + a2 * 32 + c2;
#pragma unroll
                    for (int r = 0; r < 4; r++)
                        o2[rowOff + 2 * (bb + r)] = f2bf(acc[mi][ni][r] + bv);
                } else {
                    const float* bias  = (mat == 0) ? b0 : b1;
                    unsigned short* op = (mat == 0) ? o0 : o1;
                    float bv = bias[nn];
                    float scl = (mat == 0) ? 0.18033688f : 1.0f;  // dk^-0.5 * log2e
#pragma unroll
                    for (int r = 0; r < 4; r++) {
                        float cv = (acc[mi][ni][r] + bv) * scl;
                        op[(((size_t)b * NHEADS + h) * S_LEN + (sidx + r)) * 64 + d] = f2bf(cv);
                    }
                }
            }
        }
    }
}

// ---------------- flash attention, oscillatory coherence ------------------------
// grid = 512 blocks (2 per CU), 256 thr (4 waves x 32 Q-rows = 128 Q-rows/block).
// XCD-swizzled: XCD = bid%8 owns bh-groups {4*xcd..4*xcd+3} -> K/V L2-resident.
// Each wave owns TWO 16-row halves: K/V frags read once from LDS, used by both.
// Double-buffered async staging, 1 barrier/iter. (R9 structure, proven 58.0us.)
__global__ __launch_bounds__(256, 2) void attn_kernel(
    const unsigned short* __restrict__ Qg, const unsigned short* __restrict__ Kg,
    const unsigned short* __restrict__ VTg,
    const float* __restrict__ cosP, const float* __restrict__ sinP,
    const float* __restrict__ alpha, unsigned short* __restrict__ ctx) {
    __shared__ __align__(16) unsigned short KsB[2][64 * 64];
    __shared__ __align__(16) unsigned short VtB[2][64 * 64];
    __shared__ __align__(16) float csB[2][128];          // cos 0..63, sin 64..127
    __shared__ __align__(16) unsigned short Plb[4][32 * 72];

    int x = blockIdx.x;                     // 0..511
    int bh = (x & 7) * 4 + (x >> 7);        // XCD (x%8) owns 4 consecutive bh groups
    int qt = (x >> 3) & 15;                 // 16 Q-tiles of 128 rows per bh
    int t = threadIdx.x, w = t >> 6, lane = t & 63, l15 = lane & 15, quad = lane >> 4;
    int m0 = qt * 128 + w * 32;             // wave's 32 Q-rows
    size_t base = (size_t)bh * (S_LEN * 64);
    size_t phBase = (size_t)bh * S_LEN;
    const float L2E = 1.44269504f;

    // staging geometry: thread t owns 16B chunks t and t+256 of each 8 KB tile
    int sj0 = t >> 3, sg = t & 7;
    int srot = ((sg - (sj0 & 7)) & 7) * 8;  // shorts; same rotation for sj0+32 (32&7==0)
    int sj1 = sj0 + 32;

    // Q frags (A-layout) for both row-halves; Q pre-scaled by 0.125*L2E
    short8 qf[2][2];
#pragma unroll
    for (int rh = 0; rh < 2; rh++)
#pragma unroll
        for (int c = 0; c < 2; c++)
            qf[rh][c] = *reinterpret_cast<const short8*>(
                &Qg[base + (size_t)(m0 + rh * 16 + l15) * 64 + c * 32 + quad * 8]);

    float alph = alpha[bh & 15] * L2E;
    // per-output-row coherence coefficients, packed in row pairs for v_pk_fma_f32
    float2v ci2[2][2], si2[2][2];
#pragma unroll
    for (int rh = 0; rh < 2; rh++)
#pragma unroll
        for (int hh = 0; hh < 2; hh++) {
            size_t o = phBase + m0 + rh * 16 + quad * 4 + hh * 2;
            ci2[rh][hh] = (float2v){alph * cosP[o], alph * cosP[o + 1]};
            si2[rh][hh] = (float2v){alph * sinP[o], alph * sinP[o + 1]};
        }

    {   // stage kt=0 -> buf 0
        async_copy16(&Kg[base + (size_t)sj0 * 64 + srot], &KsB[0][t * 8]);
        async_copy16(&Kg[base + (size_t)sj1 * 64 + srot], &KsB[0][(t + 256) * 8]);
        async_copy16(&VTg[base + (size_t)sj0 * S_LEN + srot], &VtB[0][t * 8]);
        async_copy16(&VTg[base + (size_t)sj1 * S_LEN + srot], &VtB[0][(t + 256) * 8]);
        if (w == 2)      async_copy4(&cosP[phBase + lane], &csB[0][lane]);
        else if (w == 3) async_copy4(&sinP[phBase + lane], &csB[0][64 + lane]);
    }

    floatx4 oacc[2][4], lacc[2];
#pragma unroll
    for (int rh = 0; rh < 2; rh++) {
#pragma unroll
        for (int tt = 0; tt < 4; tt++) oacc[rh][tt] = (floatx4){0.f, 0.f, 0.f, 0.f};
        lacc[rh] = (floatx4){0.f, 0.f, 0.f, 0.f};
    }
    const short8 ones8 = {(short)0x3F80, (short)0x3F80, (short)0x3F80, (short)0x3F80,
                          (short)0x3F80, (short)0x3F80, (short)0x3F80, (short)0x3F80};

    // frag-read rotation
    int rot = l15 & 7;
    int cb0 = 16 * ((quad + rot) & 7);        // bytes, k-chunk c=0
    int cb1 = 16 * ((quad + 4 + rot) & 7);    // bytes, k-chunk c=1

    for (int kt = 0; kt < 32; kt++) {
        int p = kt & 1;
        __syncthreads();   // drains async copies for kt; buf p^1 free
        if (kt < 31) {
            int kn = kt + 1, pn = p ^ 1;
            async_copy16(&Kg[base + (size_t)(kn * 64 + sj0) * 64 + srot], &KsB[pn][t * 8]);
            async_copy16(&Kg[base + (size_t)(kn * 64 + sj1) * 64 + srot], &KsB[pn][(t + 256) * 8]);
            async_copy16(&VTg[base + (size_t)sj0 * S_LEN + kn * 64 + srot], &VtB[pn][t * 8]);
            async_copy16(&VTg[base + (size_t)sj1 * S_LEN + kn * 64 + srot], &VtB[pn][(t + 256) * 8]);
            if (w == 2)      async_copy4(&cosP[phBase + kn * 64 + lane], &csB[pn][lane]);
            else if (w == 3) async_copy4(&sinP[phBase + kn * 64 + lane], &csB[pn][64 + lane]);
        }

        // QK^T: both row-halves share each K-frag read
        floatx4 st[2][4];
#pragma unroll
        for (int jt = 0; jt < 4; jt++) {
            const char* kr = (const char*)&KsB[p][(jt * 16 + l15) * 64];
            short8 kf0 = *reinterpret_cast<const short8*>(kr + cb0);
            short8 kf1 = *reinterpret_cast<const short8*>(kr + cb1);
#pragma unroll
            for (int rh = 0; rh < 2; rh++) {
                floatx4 s = (floatx4){0.f, 0.f, 0.f, 0.f};
                s = __builtin_amdgcn_mfma_f32_16x16x32_bf16(qf[rh][0], kf0, s, 0, 0, 0);
                s = __builtin_amdgcn_mfma_f32_16x16x32_bf16(qf[rh][1], kf1, s, 0, 0, 0);
                st[rh][jt] = s;
            }
        }

        float cjv[4], sjv[4];
#pragma unroll
        for (int jt = 0; jt < 4; jt++) {
            cjv[jt] = csB[p][jt * 16 + l15];
            sjv[jt] = csB[p][64 + jt * 16 + l15];
        }

        // P = exp2(S + coherence) -> packed bf16 in Plb[w] (pi column order).
        // Coherence computed on row-pairs: fma(si,sjv,fma(ci,cjv,st)) -> v_pk_fma_f32.
        unsigned int* pl = reinterpret_cast<unsigned int*>(&Plb[w][0]);
#pragma unroll
        for (int rh = 0; rh < 2; rh++)
#pragma unroll
            for (int rp = 0; rp < 2; rp++) {
                float2v a0, a1, a2, a3;
                {
                    float2v s0 = (float2v){st[rh][0][rp * 2], st[rh][0][rp * 2 + 1]};
                    float2v s1 = (float2v){st[rh][1][rp * 2], st[rh][1][rp * 2 + 1]};
                    float2v s2 = (float2v){st[rh][2][rp * 2], st[rh][2][rp * 2 + 1]};
                    float2v s3 = (float2v){st[rh][3][rp * 2], st[rh][3][rp * 2 + 1]};
                    a0 = si2[rh][rp] * sjv[0] + (ci2[rh][rp] * cjv[0] + s0);
                    a1 = si2[rh][rp] * sjv[1] + (ci2[rh][rp] * cjv[1] + s1);
                    a2 = si2[rh][rp] * sjv[2] + (ci2[rh][rp] * cjv[2] + s2);
                    a3 = si2[rh][rp] * sjv[3] + (ci2[rh][rp] * cjv[3] + s3);
                }
                int row = rh * 16 + quad * 4 + rp * 2;
                pl[row * 36 + l15]      = pack2_bf16(__builtin_amdgcn_exp2f(a1.x),
                                                     __builtin_amdgcn_exp2f(a0.x));
                pl[row * 36 + 16 + l15] = pack2_bf16(__builtin_amdgcn_exp2f(a3.x),
                                                     __builtin_amdgcn_exp2f(a2.x));
                pl[(row + 1) * 36 + l15]      = pack2_bf16(__builtin_amdgcn_exp2f(a1.y),
                                                           __builtin_amdgcn_exp2f(a0.y));
                pl[(row + 1) * 36 + 16 + l15] = pack2_bf16(__builtin_amdgcn_exp2f(a3.y),
                                                           __builtin_amdgcn_exp2f(a2.y));
            }

        // P A-frags (rows i, pi-ordered k), per row-half
        short8 pf[2][2];
#pragma unroll
        for (int rh = 0; rh < 2; rh++)
#pragma unroll
            for (int c = 0; c < 2; c++)
                pf[rh][c] = *reinterpret_cast<const short8*>(
                    &Plb[w][(rh * 16 + l15) * 72 + c * 32 + quad * 8]);

        // O += P @ V; l += P @ ones — V frags shared across row-halves
#pragma unroll
        for (int c = 0; c < 2; c++) {
            int cb = c ? cb1 : cb0;
#pragma unroll
            for (int tt = 0; tt < 4; tt++) {
                const char* vr = (const char*)&VtB[p][(tt * 16 + l15) * 64];
                short8 vf = *reinterpret_cast<const short8*>(vr + cb);
                oacc[0][tt] = __builtin_amdgcn_mfma_f32_16x16x32_bf16(pf[0][c], vf, oacc[0][tt], 0, 0, 0);
                oacc[1][tt] = __builtin_amdgcn_mfma_f32_16x16x32_bf16(pf[1][c], vf, oacc[1][tt], 0, 0, 0);
            }
            lacc[0] = __builtin_amdgcn_mfma_f32_16x16x32_bf16(pf[0][c], ones8, lacc[0], 0, 0, 0);
            lacc[1] = __builtin_amdgcn_mfma_f32_16x16x32_bf16(pf[1][c], ones8, lacc[1], 0, 0, 0);
        }
    }

    // epilogue: normalize rows by l and write ctx[b][s][h*64+d]
    int b = bh >> 4, h = bh & 15;
#pragma unroll
    for (int rh = 0; rh < 2; rh++) {
        float inv[4];
#pragma unroll
        for (int r = 0; r < 4; r++) inv[r] = 1.0f / lacc[rh][r];
#pragma unroll
        for (int tt = 0; tt < 4; tt++)
#pragma unroll
            for (int r = 0; r < 4; r++) {
                int srow = m0 + rh * 16 + quad * 4 + r;
                ctx[((size_t)(b * S_LEN + srow)) * 1024 + h * 64 + tt * 16 + l15] =
                    f2bf(oacc[rh][tt][r] * inv[r]);
            }
    }
}

extern "C" void kernel_launch(void* const* d_in, const int* in_sizes, int n_in,
                              void* d_out, int out_size, void* d_ws, size_t ws_size,
                              hipStream_t stream) {
    const float* x     = (const float*)d_in[0];
    const float* Wq    = (const float*)d_in[1];
    const float* bq    = (const float*)d_in[2];
    const float* Wk    = (const float*)d_in[3];
    const float* bk    = (const float*)d_in[4];
    const float* Wv    = (const float*)d_in[5];
    const float* bv    = (const float*)d_in[6];
    const float* Wo    = (const float*)d_in[7];
    const float* bo    = (const float*)d_in[8];
    const float* Wp    = (const float*)d_in[9];
    const float* bp    = (const float*)d_in[10];
    const float* alpha = (const float*)d_in[11];
    float* out = (float*)d_out;

    const size_t MB = 1048576;
    char* ws = (char*)d_ws;
    unsigned short* WT   = (unsigned short*)(ws);             // 3072x1024 bf16
    unsigned short* WoT  = (unsigned short*)(ws + 6 * MB);    // 1024x1024 bf16
    unsigned short* xb   = (unsigned short*)(ws + 8 * MB);    // (B,S,D) bf16
    unsigned short* ctx  = (unsigned short*)(ws + 8 * MB);    // aliases xb
    unsigned short* Qw   = (unsigned short*)(ws + 16 * MB);   // (B,H,S,dk), pre-scaled
    unsigned short* Kw   = (unsigned short*)(ws + 24 * MB);   // (B,H,S,dk)
    unsigned short* VTg  = (unsigned short*)(ws + 32 * MB);   // (B,H,dk,S) pi-interleaved
    float* cosP          = (float*)(ws + 40 * MB);
    float* sinP          = (float*)(ws + 40 * MB + 262144);

    prep_kernel<<<dim3(5120), dim3(256), 0, stream>>>(
        x, Wp, bp, Wq, Wk, Wv, Wo,
        WT, WT + 1048576, WT + 2097152, WoT, cosP, sinP, xb);
    gemm_bt<128><<<dim3(32, 24), dim3(256), 0, stream>>>(
        xb, WT, 3072, 1, bq, bk, bv, Qw, Kw, VTg, (float*)nullptr);
    attn_kernel<<<dim3(512), dim3(256), 0, stream>>>(
        Qw, Kw, VTg, cosP, sinP, alpha, ctx);
    gemm_bt<64><<<dim3(64, 8), dim3(256), 0, stream>>>(
        ctx, WoT, 1024, 0, bo, bo, bo,
        (unsigned short*)nullptr, (unsigned short*)nullptr,
        (unsigned short*)nullptr, out);
}

// Round 8
// 214.521 us; speedup vs baseline: 1.0905x; 1.0905x over previous
//
#include <hip/hip_runtime.h>
#include <math.h>

// OscillatoryAttention: B=2,S=2048,D=1024,H=16,dk=64. FP32 in/out, bf16 MFMA inside.
// R14: restore R7-best config (attn 1024-thr grid-256 = 57.2us; baseline BK=32 GEMMs;
//      MT=64 O-proj). Fix prep phase GEMV with PROPER coalescing: x row staged in LDS,
//      16 fully-coalesced float4 Wp loads/thread (16B lane stride), LDS float4 reduce.
//      (R13's version had 256B lane stride = uncoalesced -> regressed.)

#define S_LEN 2048
#define NHEADS 16

typedef __attribute__((ext_vector_type(8))) short short8;
typedef __attribute__((ext_vector_type(4))) float floatx4;
typedef __attribute__((ext_vector_type(2))) float float2v;
typedef __attribute__((ext_vector_type(4))) unsigned int uintx4;

__device__ inline unsigned short f2bf(float f) {
    union { float f; unsigned int i; } v; v.f = f;
    unsigned int u = v.i;
    return (unsigned short)((u + 0x7fffu + ((u >> 16) & 1u)) >> 16);
}
// pack two f32 -> packed bf16 u32 (truncation), low short = lo
__device__ inline unsigned int pack2_bf16(float hi, float lo) {
    union { float f; unsigned int u; } a, b; a.f = hi; b.f = lo;
    return __builtin_amdgcn_perm(a.u, b.u, 0x07060302u);
}
__device__ inline void async_copy16(const unsigned short* src, unsigned short* dst_lds) {
    __builtin_amdgcn_global_load_lds(
        (const __attribute__((address_space(1))) unsigned int*)(src),
        (__attribute__((address_space(3))) unsigned int*)(dst_lds), 16, 0, 0);
}
__device__ inline void async_copy4(const float* src, float* dst_lds) {
    __builtin_amdgcn_global_load_lds(
        (const __attribute__((address_space(1))) unsigned int*)(src),
        (__attribute__((address_space(3))) unsigned int*)(dst_lds), 4, 0, 0);
}

// ---------------- prep: phase+cvt (blocks 0..4095) | weight transpose (4096..5119)
// Phase branch: x row -> LDS f32; Wp read with 16 coalesced float4 loads/thread
// (lane stride 16B): thread t covers Wp rows k=i*64+t/4, h-block (t&3)*4.
// Reduce via LDS float4 table; threads 0..15 finish + sincos.
__global__ __launch_bounds__(256) void prep_kernel(
    const float* __restrict__ x, const float* __restrict__ Wp,
    const float* __restrict__ bp,
    const float* __restrict__ w0, const float* __restrict__ w1,
    const float* __restrict__ w2, const float* __restrict__ w3,
    unsigned short* __restrict__ d0, unsigned short* __restrict__ d1,
    unsigned short* __restrict__ d2, unsigned short* __restrict__ d3,
    float* __restrict__ cosP, float* __restrict__ sinP,
    unsigned short* __restrict__ xb) {
    __shared__ __align__(16) unsigned short shmem[64 * 72];   // 9216 B union
    int t = threadIdx.x;
    if (blockIdx.x < 4096) {
        float* fb = reinterpret_cast<float*>(shmem);
        float* xs = fb;                                        // [1024] f32 x row
        float4* red4 = reinterpret_cast<float4*>(fb + 1024);   // [256] float4 partials
        int bid = blockIdx.x;
        int b = bid >> 11, s = bid & 2047;
        const float* xr = x + (size_t)bid * 1024;
        float4 xv = *reinterpret_cast<const float4*>(&xr[t * 4]);
        {
            uint2 o;
            o.x = (unsigned int)f2bf(xv.x) | ((unsigned int)f2bf(xv.y) << 16);
            o.y = (unsigned int)f2bf(xv.z) | ((unsigned int)f2bf(xv.w) << 16);
            *reinterpret_cast<uint2*>(&xb[(size_t)bid * 1024 + t * 4]) = o;
        }
        *reinterpret_cast<float4*>(&xs[t * 4]) = xv;
        __syncthreads();
        // coalesced GEMV: thread t owns h-block (t&3)*4, k rows i*64 + (t>>2)
        float f0 = 0.f, f1 = 0.f, f2 = 0.f, f3 = 0.f;
        int krow = t >> 2;
        const float4* wp4 = reinterpret_cast<const float4*>(Wp);
#pragma unroll
        for (int i = 0; i < 16; i++) {
            float4 wv = wp4[i * 256 + t];          // lane stride 16B: coalesced
            float xk = xs[i * 64 + krow];          // 4-lane broadcast, conflict-free
            f0 += xk * wv.x; f1 += xk * wv.y; f2 += xk * wv.z; f3 += xk * wv.w;
        }
        red4[t] = make_float4(f0, f1, f2, f3);
        __syncthreads();
        if (t < 16) {
            // h = t: contributors are threads 4j + (t>>2), component t&3
            int b2 = t >> 2, comp = t & 3;
            const float* rf = fb + 1024;           // scalar view of red4
            float sum = bp[t];
#pragma unroll
            for (int j = 0; j < 64; j++) sum += rf[(4 * j + b2) * 4 + comp];
            float sv, cv;
            __sincosf(sum, &sv, &cv);
            size_t o = ((size_t)b * NHEADS + t) * S_LEN + s;
            cosP[o] = cv; sinP[o] = sv;
        }
    } else {
        unsigned short (*tile)[72] = reinterpret_cast<unsigned short (*)[72]>(shmem);
        int bid = blockIdx.x - 4096;
        int mat = bid >> 8;
        int tl  = bid & 255;
        int tr = tl >> 4, tc = tl & 15;
        const float* src    = (mat == 0) ? w0 : (mat == 1) ? w1 : (mat == 2) ? w2 : w3;
        unsigned short* dst = (mat == 0) ? d0 : (mat == 1) ? d1 : (mat == 2) ? d2 : d3;
        int col = t & 63, rbase = (t >> 6) * 16;
#pragma unroll
        for (int i = 0; i < 16; i++) {
            int row = rbase + i;
            tile[row][col] = f2bf(src[(size_t)(tr * 64 + row) * 1024 + tc * 64 + col]);
        }
        __syncthreads();
#pragma unroll
        for (int i = 0; i < 16; i++) {
            int row = rbase + i;
            dst[(size_t)(tc * 64 + row) * 1024 + tr * 64 + col] = tile[col][row];
        }
    }
}

// ---------------- GEMM (m97 recipe, baseline BK=32) ------------------------------
// mode 0: row-major fp32 out (+bias) -> of
// mode 1: N=3072 QKV: Q scaled 0.125*log2e -> (B,H,S,dk); K -> (B,H,S,dk);
//         V -> (B,H,dk,S) transposed AND pi-interleaved within 64-token chunks:
//         token j=32a+16c+b lands at short u=32a+2b+c.
template <int MT>
__global__ __launch_bounds__(256) void gemm_bt(
    const unsigned short* __restrict__ A, const unsigned short* __restrict__ BT,
    int N, int mode,
    const float* __restrict__ b0, const float* __restrict__ b1,
    const float* __restrict__ b2,
    unsigned short* __restrict__ o0, unsigned short* __restrict__ o1,
    unsigned short* __restrict__ o2, float* __restrict__ of) {
    __shared__ __align__(16) unsigned short As[MT * 32];
    __shared__ __align__(16) unsigned short Bs[128 * 32];
    const int K = 1024;
    const int MI = MT / 32;
    int t = threadIdx.x;
    int mBase = blockIdx.x * MT;
    int nBase = blockIdx.y * 128;
    int w = t >> 6, lane = t & 63, l15 = lane & 15, quad = lane >> 4;
    int wm = (w & 1) * (MT / 2), wn = (w >> 1) * 64;
    floatx4 acc[MI][4];
#pragma unroll
    for (int i = 0; i < MI; i++)
#pragma unroll
        for (int j = 0; j < 4; j++) acc[i][j] = (floatx4){0.f, 0.f, 0.f, 0.f};

    int arow = t >> 2, aseg = (t & 3) * 8;
    for (int k0 = 0; k0 < K; k0 += 32) {
        __syncthreads();
#pragma unroll
        for (int i = 0; i < MT / 64; i++)
            async_copy16(&A[(size_t)(mBase + i * 64 + arow) * K + k0 + aseg],
                         &As[(i * 64 + arow) * 32 + aseg]);
#pragma unroll
        for (int i = 0; i < 2; i++)
            async_copy16(&BT[(size_t)(nBase + i * 64 + arow) * K + k0 + aseg],
                         &Bs[(i * 64 + arow) * 32 + aseg]);
        __syncthreads();
        short8 af[MI], bfr[4];
#pragma unroll
        for (int mi = 0; mi < MI; mi++)
            af[mi] = *reinterpret_cast<const short8*>(&As[(wm + mi * 16 + l15) * 32 + quad * 8]);
#pragma unroll
        for (int ni = 0; ni < 4; ni++)
            bfr[ni] = *reinterpret_cast<const short8*>(&Bs[(wn + ni * 16 + l15) * 32 + quad * 8]);
#pragma unroll
        for (int mi = 0; mi < MI; mi++)
#pragma unroll
            for (int ni = 0; ni < 4; ni++)
                acc[mi][ni] = __builtin_amdgcn_mfma_f32_16x16x32_bf16(af[mi], bfr[ni], acc[mi][ni], 0, 0, 0);
    }

#pragma unroll
    for (int mi = 0; mi < MI; mi++) {
        int rowB = mBase + wm + mi * 16 + quad * 4;
#pragma unroll
        for (int ni = 0; ni < 4; ni++) {
            int col = nBase + wn + ni * 16 + l15;
            if (mode == 0) {
                float bias = b0[col];
#pragma unroll
                for (int r = 0; r < 4; r++) {
                    of[(size_t)(rowB + r) * N + col] = acc[mi][ni][r] + bias;
                }
            } else {
                int mat = col >> 10, nn = col & 1023;
                int h = nn >> 6, d = nn & 63;
                int b = rowB >> 11, sidx = rowB & 2047;
                if (mat == 2) {
                    float bv = b2[nn];
                    int jj = sidx & 63;                 // multiple of 4
                    int a2 = jj >> 5, c2 = (jj >> 4) & 1, bb = jj & 15;
                    size_t rowOff = ((size_t)((b * NHEADS + h) * 64 + d)) * S_LEN +
                                    (sidx & ~63) + a2 * 32 + c2;
#pragma unroll
                    for (int r = 0; r < 4; r++)
                        o2[rowOff + 2 * (bb + r)] = f2bf(acc[mi][ni][r] + bv);
                } else {
                    const float* bias  = (mat == 0) ? b0 : b1;
                    unsigned short* op = (mat == 0) ? o0 : o1;
                    float bv = bias[nn];
                    float scl = (mat == 0) ? 0.18033688f : 1.0f;  // dk^-0.5 * log2e
#pragma unroll
                    for (int r = 0; r < 4; r++) {
                        float cv = (acc[mi][ni][r] + bv) * scl;
                        op[(((size_t)b * NHEADS + h) * S_LEN + (sidx + r)) * 64 + d] = f2bf(cv);
                    }
                }
            }
        }
    }
}

// ---------------- flash attention, oscillatory coherence ------------------------
// grid = 256 blocks (1 per CU), 1024 thr (16 waves x 16 Q-rows = 256 Q-rows/block).
// XCD-swizzled: XCD = bid%8 owns 4 bh-groups -> K/V L2-resident. (R7 structure,
// best measured attn: 57.2us.)
__global__ __launch_bounds__(1024) void attn_kernel(
    const unsigned short* __restrict__ Qg, const unsigned short* __restrict__ Kg,
    const unsigned short* __restrict__ VTg,
    const float* __restrict__ cosP, const float* __restrict__ sinP,
    const float* __restrict__ alpha, unsigned short* __restrict__ ctx) {
    __shared__ __align__(16) unsigned short KsB[2][64 * 64];
    __shared__ __align__(16) unsigned short VtB[2][64 * 64];
    __shared__ __align__(16) float csB[2][128];          // cos 0..63, sin 64..127
    __shared__ __align__(16) unsigned short Plb[16][16 * 72];

    int x = blockIdx.x;                     // 0..255
    int bh = (x & 7) * 4 + (x >> 6);        // XCD (x%8) owns 4 consecutive bh groups
    int qt = (x >> 3) & 7;                  // 8 Q-tiles of 256 rows per bh
    int t = threadIdx.x, w = t >> 6, lane = t & 63, l15 = lane & 15, quad = lane >> 4;
    int m0 = qt * 256 + w * 16;
    size_t base = (size_t)bh * (S_LEN * 64);
    size_t phBase = (size_t)bh * S_LEN;
    const float L2E = 1.44269504f;

    // staging geometry: threads 0..511 own K bytes [16t,16t+16), 512..1023 own V
    int th = t & 511;
    int sj = th >> 3, sg = th & 7;
    int srot = ((sg - (sj & 7)) & 7) * 8;   // shorts: un-rotated global column
    bool stK = (t < 512);

    // Q frags (A-layout); Q pre-scaled by 0.125*L2E
    short8 qf[2];
#pragma unroll
    for (int c = 0; c < 2; c++)
        qf[c] = *reinterpret_cast<const short8*>(
            &Qg[base + (size_t)(m0 + l15) * 64 + c * 32 + quad * 8]);

    float alph = alpha[bh & 15] * L2E;
    // per-output-row coherence coefficients, packed in row pairs for v_pk_fma_f32
    float2v ci2[2], si2[2];
#pragma unroll
    for (int hh = 0; hh < 2; hh++) {
        size_t o = phBase + m0 + quad * 4 + hh * 2;
        ci2[hh] = (float2v){alph * cosP[o], alph * cosP[o + 1]};
        si2[hh] = (float2v){alph * sinP[o], alph * sinP[o + 1]};
    }

    {   // stage kt=0 -> buf 0
        if (stK) async_copy16(&Kg[base + (size_t)sj * 64 + srot], &KsB[0][th * 8]);
        else     async_copy16(&VTg[base + (size_t)sj * S_LEN + srot], &VtB[0][th * 8]);
        if (w == 4)      async_copy4(&cosP[phBase + lane], &csB[0][lane]);
        else if (w == 5) async_copy4(&sinP[phBase + lane], &csB[0][64 + lane]);
    }

    floatx4 oacc[4], lacc;
#pragma unroll
    for (int tt = 0; tt < 4; tt++) oacc[tt] = (floatx4){0.f, 0.f, 0.f, 0.f};
    lacc = (floatx4){0.f, 0.f, 0.f, 0.f};
    const short8 ones8 = {(short)0x3F80, (short)0x3F80, (short)0x3F80, (short)0x3F80,
                          (short)0x3F80, (short)0x3F80, (short)0x3F80, (short)0x3F80};

    // frag-read rotation
    int rot = l15 & 7;
    int cb0 = 16 * ((quad + rot) & 7);        // bytes, k-chunk c=0
    int cb1 = 16 * ((quad + 4 + rot) & 7);    // bytes, k-chunk c=1

    for (int kt = 0; kt < 32; kt++) {
        int p = kt & 1;
        __syncthreads();   // drains async copies for kt; buf p^1 free
        if (kt < 31) {
            int kn = kt + 1, pn = p ^ 1;
            if (stK) async_copy16(&Kg[base + (size_t)(kn * 64 + sj) * 64 + srot], &KsB[pn][th * 8]);
            else     async_copy16(&VTg[base + (size_t)sj * S_LEN + kn * 64 + srot], &VtB[pn][th * 8]);
            if (w == 4)      async_copy4(&cosP[phBase + kn * 64 + lane], &csB[pn][lane]);
            else if (w == 5) async_copy4(&sinP[phBase + kn * 64 + lane], &csB[pn][64 + lane]);
        }

        // QK^T: S(i,j) C-layout (i=quad*4+r, j=l15 per 16-subtile)
        floatx4 st[4];
#pragma unroll
        for (int jt = 0; jt < 4; jt++) {
            const char* kr = (const char*)&KsB[p][(jt * 16 + l15) * 64];
            short8 kf0 = *reinterpret_cast<const short8*>(kr + cb0);
            short8 kf1 = *reinterpret_cast<const short8*>(kr + cb1);
            floatx4 s = (floatx4){0.f, 0.f, 0.f, 0.f};
            s = __builtin_amdgcn_mfma_f32_16x16x32_bf16(qf[0], kf0, s, 0, 0, 0);
            s = __builtin_amdgcn_mfma_f32_16x16x32_bf16(qf[1], kf1, s, 0, 0, 0);
            st[jt] = s;
        }

        float cjv[4], sjv[4];
#pragma unroll
        for (int jt = 0; jt < 4; jt++) {
            cjv[jt] = csB[p][jt * 16 + l15];
            sjv[jt] = csB[p][64 + jt * 16 + l15];
        }

        // P = exp2(S + coherence) -> packed bf16 in Plb[w] (pi column order).
        // Coherence computed on row-pairs: fma(si,sjv,fma(ci,cjv,st)) -> v_pk_fma_f32.
        unsigned int* pl = reinterpret_cast<unsigned int*>(&Plb[w][0]);
#pragma unroll
        for (int rp = 0; rp < 2; rp++) {
            float2v a0, a1, a2, a3;
            {
                float2v s0 = (float2v){st[0][rp * 2], st[0][rp * 2 + 1]};
                float2v s1 = (float2v){st[1][rp * 2], st[1][rp * 2 + 1]};
                float2v s2 = (float2v){st[2][rp * 2], st[2][rp * 2 + 1]};
                float2v s3 = (float2v){st[3][rp * 2], st[3][rp * 2 + 1]};
                a0 = si2[rp] * sjv[0] + (ci2[rp] * cjv[0] + s0);
                a1 = si2[rp] * sjv[1] + (ci2[rp] * cjv[1] + s1);
                a2 = si2[rp] * sjv[2] + (ci2[rp] * cjv[2] + s2);
                a3 = si2[rp] * sjv[3] + (ci2[rp] * cjv[3] + s3);
            }
            int row = quad * 4 + rp * 2;
            pl[row * 36 + l15]      = pack2_bf16(__builtin_amdgcn_exp2f(a1.x),
                                                 __builtin_amdgcn_exp2f(a0.x));
            pl[row * 36 + 16 + l15] = pack2_bf16(__builtin_amdgcn_exp2f(a3.x),
                                                 __builtin_amdgcn_exp2f(a2.x));
            pl[(row + 1) * 36 + l15]      = pack2_bf16(__builtin_amdgcn_exp2f(a1.y),
                                                       __builtin_amdgcn_exp2f(a0.y));
            pl[(row + 1) * 36 + 16 + l15] = pack2_bf16(__builtin_amdgcn_exp2f(a3.y),
                                                       __builtin_amdgcn_exp2f(a2.y));
        }

        // P A-frags (rows i, pi-ordered k)
        short8 pf[2];
#pragma unroll
        for (int c = 0; c < 2; c++)
            pf[c] = *reinterpret_cast<const short8*>(
                &Plb[w][l15 * 72 + c * 32 + quad * 8]);

        // O += P @ V; l += P @ ones
#pragma unroll
        for (int c = 0; c < 2; c++) {
            int cb = c ? cb1 : cb0;
#pragma unroll
            for (int tt = 0; tt < 4; tt++) {
                const char* vr = (const char*)&VtB[p][(tt * 16 + l15) * 64];
                short8 vf = *reinterpret_cast<const short8*>(vr + cb);
                oacc[tt] = __builtin_amdgcn_mfma_f32_16x16x32_bf16(pf[c], vf, oacc[tt], 0, 0, 0);
            }
            lacc = __builtin_amdgcn_mfma_f32_16x16x32_bf16(pf[c], ones8, lacc, 0, 0, 0);
        }
    }

    // epilogue: normalize rows by l and write ctx[b][s][h*64+d]
    int b = bh >> 4, h = bh & 15;
    float inv[4];
#pragma unroll
    for (int r = 0; r < 4; r++) inv[r] = 1.0f / lacc[r];
#pragma unroll
    for (int tt = 0; tt < 4; tt++)
#pragma unroll
        for (int r = 0; r < 4; r++) {
            int srow = m0 + quad * 4 + r;
            ctx[((size_t)(b * S_LEN + srow)) * 1024 + h * 64 + tt * 16 + l15] =
                f2bf(oacc[tt][r] * inv[r]);
        }
}

extern "C" void kernel_launch(void* const* d_in, const int* in_sizes, int n_in,
                              void* d_out, int out_size, void* d_ws, size_t ws_size,
                              hipStream_t stream) {
    const float* x     = (const float*)d_in[0];
    const float* Wq    = (const float*)d_in[1];
    const float* bq    = (const float*)d_in[2];
    const float* Wk    = (const float*)d_in[3];
    const float* bk    = (const float*)d_in[4];
    const float* Wv    = (const float*)d_in[5];
    const float* bv    = (const float*)d_in[6];
    const float* Wo    = (const float*)d_in[7];
    const float* bo    = (const float*)d_in[8];
    const float* Wp    = (const float*)d_in[9];
    const float* bp    = (const float*)d_in[10];
    const float* alpha = (const float*)d_in[11];
    float* out = (float*)d_out;

    const size_t MB = 1048576;
    char* ws = (char*)d_ws;
    unsigned short* WT   = (unsigned short*)(ws);             // 3072x1024 bf16
    unsigned short* WoT  = (unsigned short*)(ws + 6 * MB);    // 1024x1024 bf16
    unsigned short* xb   = (unsigned short*)(ws + 8 * MB);    // (B,S,D) bf16
    unsigned short* ctx  = (unsigned short*)(ws + 8 * MB);    // aliases xb
    unsigned short* Qw   = (unsigned short*)(ws + 16 * MB);   // (B,H,S,dk), pre-scaled
    unsigned short* Kw   = (unsigned short*)(ws + 24 * MB);   // (B,H,S,dk)
    unsigned short* VTg  = (unsigned short*)(ws + 32 * MB);   // (B,H,dk,S) pi-interleaved
    float* cosP          = (float*)(ws + 40 * MB);
    float* sinP          = (float*)(ws + 40 * MB + 262144);

    prep_kernel<<<dim3(5120), dim3(256), 0, stream>>>(
        x, Wp, bp, Wq, Wk, Wv, Wo,
        WT, WT + 1048576, WT + 2097152, WoT, cosP, sinP, xb);
    gemm_bt<128><<<dim3(32, 24), dim3(256), 0, stream>>>(
        xb, WT, 3072, 1, bq, bk, bv, Qw, Kw, VTg, (float*)nullptr);
    attn_kernel<<<dim3(256), dim3(1024), 0, stream>>>(
        Qw, Kw, VTg, cosP, sinP, alpha, ctx);
    gemm_bt<64><<<dim3(64, 8), dim3(256), 0, stream>>>(
        ctx, WoT, 1024, 0, bo, bo, bo,
        (unsigned short*)nullptr, (unsigned short*)nullptr,
        (unsigned short*)nullptr, out);
}

// Round 9
// 211.781 us; speedup vs baseline: 1.1047x; 1.0129x over previous
//
#include <hip/hip_runtime.h>
#include <math.h>

// OscillatoryAttention: B=2,S=2048,D=1024,H=16,dk=64. FP32 in/out, bf16 MFMA inside.
// R15: attn staging global_load_lds -> T14 reg-staging (issue-early global->reg,
//      ds_write-late). Mechanism: compiler emits vmcnt(0) before every s_barrier;
//      with global_load_lds the in-flight prefetch is IN vmcnt, so every iteration
//      exposed full staging latency (the 57-59us plateau across R7/R9/R10 structures).
//      Reg-staging moves the wait to the ds_write, where the load has already landed
//      under compute. Everything else = R14 best config. Bit-identical numerics.

#define S_LEN 2048
#define NHEADS 16

typedef __attribute__((ext_vector_type(8))) short short8;
typedef __attribute__((ext_vector_type(4))) float floatx4;
typedef __attribute__((ext_vector_type(2))) float float2v;
typedef __attribute__((ext_vector_type(4))) unsigned int uintx4;

__device__ inline unsigned short f2bf(float f) {
    union { float f; unsigned int i; } v; v.f = f;
    unsigned int u = v.i;
    return (unsigned short)((u + 0x7fffu + ((u >> 16) & 1u)) >> 16);
}
// pack two f32 -> packed bf16 u32 (truncation), low short = lo
__device__ inline unsigned int pack2_bf16(float hi, float lo) {
    union { float f; unsigned int u; } a, b; a.f = hi; b.f = lo;
    return __builtin_amdgcn_perm(a.u, b.u, 0x07060302u);
}
__device__ inline void async_copy16(const unsigned short* src, unsigned short* dst_lds) {
    __builtin_amdgcn_global_load_lds(
        (const __attribute__((address_space(1))) unsigned int*)(src),
        (__attribute__((address_space(3))) unsigned int*)(dst_lds), 16, 0, 0);
}
__device__ inline void async_copy4(const float* src, float* dst_lds) {
    __builtin_amdgcn_global_load_lds(
        (const __attribute__((address_space(1))) unsigned int*)(src),
        (__attribute__((address_space(3))) unsigned int*)(dst_lds), 4, 0, 0);
}

// ---------------- prep: phase+cvt (blocks 0..4095) | weight transpose (4096..5119)
// Phase branch: x row -> LDS f32; Wp read with 16 coalesced float4 loads/thread
// (lane stride 16B): thread t covers Wp rows k=i*64+t/4, h-block (t&3)*4.
// Reduce via LDS float4 table; threads 0..15 finish + sincos.
__global__ __launch_bounds__(256) void prep_kernel(
    const float* __restrict__ x, const float* __restrict__ Wp,
    const float* __restrict__ bp,
    const float* __restrict__ w0, const float* __restrict__ w1,
    const float* __restrict__ w2, const float* __restrict__ w3,
    unsigned short* __restrict__ d0, unsigned short* __restrict__ d1,
    unsigned short* __restrict__ d2, unsigned short* __restrict__ d3,
    float* __restrict__ cosP, float* __restrict__ sinP,
    unsigned short* __restrict__ xb) {
    __shared__ __align__(16) unsigned short shmem[64 * 72];   // 9216 B union
    int t = threadIdx.x;
    if (blockIdx.x < 4096) {
        float* fb = reinterpret_cast<float*>(shmem);
        float* xs = fb;                                        // [1024] f32 x row
        float4* red4 = reinterpret_cast<float4*>(fb + 1024);   // [256] float4 partials
        int bid = blockIdx.x;
        int b = bid >> 11, s = bid & 2047;
        const float* xr = x + (size_t)bid * 1024;
        float4 xv = *reinterpret_cast<const float4*>(&xr[t * 4]);
        {
            uint2 o;
            o.x = (unsigned int)f2bf(xv.x) | ((unsigned int)f2bf(xv.y) << 16);
            o.y = (unsigned int)f2bf(xv.z) | ((unsigned int)f2bf(xv.w) << 16);
            *reinterpret_cast<uint2*>(&xb[(size_t)bid * 1024 + t * 4]) = o;
        }
        *reinterpret_cast<float4*>(&xs[t * 4]) = xv;
        __syncthreads();
        // coalesced GEMV: thread t owns h-block (t&3)*4, k rows i*64 + (t>>2)
        float f0 = 0.f, f1 = 0.f, f2 = 0.f, f3 = 0.f;
        int krow = t >> 2;
        const float4* wp4 = reinterpret_cast<const float4*>(Wp);
#pragma unroll
        for (int i = 0; i < 16; i++) {
            float4 wv = wp4[i * 256 + t];          // lane stride 16B: coalesced
            float xk = xs[i * 64 + krow];          // 4-lane broadcast, conflict-free
            f0 += xk * wv.x; f1 += xk * wv.y; f2 += xk * wv.z; f3 += xk * wv.w;
        }
        red4[t] = make_float4(f0, f1, f2, f3);
        __syncthreads();
        if (t < 16) {
            // h = t: contributors are threads 4j + (t>>2), component t&3
            int b2 = t >> 2, comp = t & 3;
            const float* rf = fb + 1024;           // scalar view of red4
            float sum = bp[t];
#pragma unroll
            for (int j = 0; j < 64; j++) sum += rf[(4 * j + b2) * 4 + comp];
            float sv, cv;
            __sincosf(sum, &sv, &cv);
            size_t o = ((size_t)b * NHEADS + t) * S_LEN + s;
            cosP[o] = cv; sinP[o] = sv;
        }
    } else {
        unsigned short (*tile)[72] = reinterpret_cast<unsigned short (*)[72]>(shmem);
        int bid = blockIdx.x - 4096;
        int mat = bid >> 8;
        int tl  = bid & 255;
        int tr = tl >> 4, tc = tl & 15;
        const float* src    = (mat == 0) ? w0 : (mat == 1) ? w1 : (mat == 2) ? w2 : w3;
        unsigned short* dst = (mat == 0) ? d0 : (mat == 1) ? d1 : (mat == 2) ? d2 : d3;
        int col = t & 63, rbase = (t >> 6) * 16;
#pragma unroll
        for (int i = 0; i < 16; i++) {
            int row = rbase + i;
            tile[row][col] = f2bf(src[(size_t)(tr * 64 + row) * 1024 + tc * 64 + col]);
        }
        __syncthreads();
#pragma unroll
        for (int i = 0; i < 16; i++) {
            int row = rbase + i;
            dst[(size_t)(tc * 64 + row) * 1024 + tr * 64 + col] = tile[col][row];
        }
    }
}

// ---------------- GEMM (m97 recipe, baseline BK=32) ------------------------------
// mode 0: row-major fp32 out (+bias) -> of
// mode 1: N=3072 QKV: Q scaled 0.125*log2e -> (B,H,S,dk); K -> (B,H,S,dk);
//         V -> (B,H,dk,S) transposed AND pi-interleaved within 64-token chunks:
//         token j=32a+16c+b lands at short u=32a+2b+c.
template <int MT>
__global__ __launch_bounds__(256) void gemm_bt(
    const unsigned short* __restrict__ A, const unsigned short* __restrict__ BT,
    int N, int mode,
    const float* __restrict__ b0, const float* __restrict__ b1,
    const float* __restrict__ b2,
    unsigned short* __restrict__ o0, unsigned short* __restrict__ o1,
    unsigned short* __restrict__ o2, float* __restrict__ of) {
    __shared__ __align__(16) unsigned short As[MT * 32];
    __shared__ __align__(16) unsigned short Bs[128 * 32];
    const int K = 1024;
    const int MI = MT / 32;
    int t = threadIdx.x;
    int mBase = blockIdx.x * MT;
    int nBase = blockIdx.y * 128;
    int w = t >> 6, lane = t & 63, l15 = lane & 15, quad = lane >> 4;
    int wm = (w & 1) * (MT / 2), wn = (w >> 1) * 64;
    floatx4 acc[MI][4];
#pragma unroll
    for (int i = 0; i < MI; i++)
#pragma unroll
        for (int j = 0; j < 4; j++) acc[i][j] = (floatx4){0.f, 0.f, 0.f, 0.f};

    int arow = t >> 2, aseg = (t & 3) * 8;
    for (int k0 = 0; k0 < K; k0 += 32) {
        __syncthreads();
#pragma unroll
        for (int i = 0; i < MT / 64; i++)
            async_copy16(&A[(size_t)(mBase + i * 64 + arow) * K + k0 + aseg],
                         &As[(i * 64 + arow) * 32 + aseg]);
#pragma unroll
        for (int i = 0; i < 2; i++)
            async_copy16(&BT[(size_t)(nBase + i * 64 + arow) * K + k0 + aseg],
                         &Bs[(i * 64 + arow) * 32 + aseg]);
        __syncthreads();
        short8 af[MI], bfr[4];
#pragma unroll
        for (int mi = 0; mi < MI; mi++)
            af[mi] = *reinterpret_cast<const short8*>(&As[(wm + mi * 16 + l15) * 32 + quad * 8]);
#pragma unroll
        for (int ni = 0; ni < 4; ni++)
            bfr[ni] = *reinterpret_cast<const short8*>(&Bs[(wn + ni * 16 + l15) * 32 + quad * 8]);
#pragma unroll
        for (int mi = 0; mi < MI; mi++)
#pragma unroll
            for (int ni = 0; ni < 4; ni++)
                acc[mi][ni] = __builtin_amdgcn_mfma_f32_16x16x32_bf16(af[mi], bfr[ni], acc[mi][ni], 0, 0, 0);
    }

#pragma unroll
    for (int mi = 0; mi < MI; mi++) {
        int rowB = mBase + wm + mi * 16 + quad * 4;
#pragma unroll
        for (int ni = 0; ni < 4; ni++) {
            int col = nBase + wn + ni * 16 + l15;
            if (mode == 0) {
                float bias = b0[col];
#pragma unroll
                for (int r = 0; r < 4; r++) {
                    of[(size_t)(rowB + r) * N + col] = acc[mi][ni][r] + bias;
                }
            } else {
                int mat = col >> 10, nn = col & 1023;
                int h = nn >> 6, d = nn & 63;
                int b = rowB >> 11, sidx = rowB & 2047;
                if (mat == 2) {
                    float bv = b2[nn];
                    int jj = sidx & 63;                 // multiple of 4
                    int a2 = jj >> 5, c2 = (jj >> 4) & 1, bb = jj & 15;
                    size_t rowOff = ((size_t)((b * NHEADS + h) * 64 + d)) * S_LEN +
                                    (sidx & ~63) + a2 * 32 + c2;
#pragma unroll
                    for (int r = 0; r < 4; r++)
                        o2[rowOff + 2 * (bb + r)] = f2bf(acc[mi][ni][r] + bv);
                } else {
                    const float* bias  = (mat == 0) ? b0 : b1;
                    unsigned short* op = (mat == 0) ? o0 : o1;
                    float bv = bias[nn];
                    float scl = (mat == 0) ? 0.18033688f : 1.0f;  // dk^-0.5 * log2e
#pragma unroll
                    for (int r = 0; r < 4; r++) {
                        float cv = (acc[mi][ni][r] + bv) * scl;
                        op[(((size_t)b * NHEADS + h) * S_LEN + (sidx + r)) * 64 + d] = f2bf(cv);
                    }
                }
            }
        }
    }
}

// ---------------- flash attention, oscillatory coherence ------------------------
// grid = 256 blocks (1 per CU), 1024 thr (16 waves x 16 Q-rows = 256 Q-rows/block).
// XCD-swizzled: XCD = bid%8 owns 4 bh-groups -> K/V L2-resident.
// R15: T14 reg-staging. Per iter: (1) issue global->reg load of next K/V chunk,
// (2) compute current tile (loads fly underneath), (3) ds_write regs -> other buf
// (vmcnt wait lands HERE, after compute), (4) one barrier (lgkmcnt only).
__global__ __launch_bounds__(1024) void attn_kernel(
    const unsigned short* __restrict__ Qg, const unsigned short* __restrict__ Kg,
    const unsigned short* __restrict__ VTg,
    const float* __restrict__ cosP, const float* __restrict__ sinP,
    const float* __restrict__ alpha, unsigned short* __restrict__ ctx) {
    __shared__ __align__(16) unsigned short KsB[2][64 * 64];
    __shared__ __align__(16) unsigned short VtB[2][64 * 64];
    __shared__ __align__(16) float csB[2][128];          // cos 0..63, sin 64..127
    __shared__ __align__(16) unsigned short Plb[16][16 * 72];

    int x = blockIdx.x;                     // 0..255
    int bh = (x & 7) * 4 + (x >> 6);        // XCD (x%8) owns 4 consecutive bh groups
    int qt = (x >> 3) & 7;                  // 8 Q-tiles of 256 rows per bh
    int t = threadIdx.x, w = t >> 6, lane = t & 63, l15 = lane & 15, quad = lane >> 4;
    int m0 = qt * 256 + w * 16;
    size_t base = (size_t)bh * (S_LEN * 64);
    size_t phBase = (size_t)bh * S_LEN;
    const float L2E = 1.44269504f;

    // staging geometry: threads 0..511 own K chunk th, 512..1023 own V chunk th
    int th = t & 511;
    int sj = th >> 3, sg = th & 7;
    int srot = ((sg - (sj & 7)) & 7) * 8;   // shorts: un-rotated global column
    bool stK = (t < 512);
    // per-thread global source base and LDS dest base (buffer-indexed)
    const unsigned short* gsrc0 = stK ? &Kg[base + (size_t)sj * 64 + srot]
                                      : &VTg[base + (size_t)sj * S_LEN + srot];
    // K tile advances by 64 rows (64*64 shorts); V tile advances by 64 columns
    size_t gstep = stK ? (size_t)64 * 64 : (size_t)64;
    unsigned short* ldst[2];
    ldst[0] = stK ? &KsB[0][th * 8] : &VtB[0][th * 8];
    ldst[1] = stK ? &KsB[1][th * 8] : &VtB[1][th * 8];

    // Q frags (A-layout); Q pre-scaled by 0.125*L2E
    short8 qf[2];
#pragma unroll
    for (int c = 0; c < 2; c++)
        qf[c] = *reinterpret_cast<const short8*>(
            &Qg[base + (size_t)(m0 + l15) * 64 + c * 32 + quad * 8]);

    float alph = alpha[bh & 15] * L2E;
    // per-output-row coherence coefficients, packed in row pairs for v_pk_fma_f32
    float2v ci2[2], si2[2];
#pragma unroll
    for (int hh = 0; hh < 2; hh++) {
        size_t o = phBase + m0 + quad * 4 + hh * 2;
        ci2[hh] = (float2v){alph * cosP[o], alph * cosP[o + 1]};
        si2[hh] = (float2v){alph * sinP[o], alph * sinP[o + 1]};
    }

    {   // prologue: tile 0 -> regs -> buf 0
        uintx4 r0 = *reinterpret_cast<const uintx4*>(gsrc0);
        if (w == 4)      async_copy4(&cosP[phBase + lane], &csB[0][lane]);
        else if (w == 5) async_copy4(&sinP[phBase + lane], &csB[0][64 + lane]);
        *reinterpret_cast<uintx4*>(ldst[0]) = r0;
    }

    floatx4 oacc[4], lacc;
#pragma unroll
    for (int tt = 0; tt < 4; tt++) oacc[tt] = (floatx4){0.f, 0.f, 0.f, 0.f};
    lacc = (floatx4){0.f, 0.f, 0.f, 0.f};
    const short8 ones8 = {(short)0x3F80, (short)0x3F80, (short)0x3F80, (short)0x3F80,
                          (short)0x3F80, (short)0x3F80, (short)0x3F80, (short)0x3F80};

    // frag-read rotation
    int rot = l15 & 7;
    int cb0 = 16 * ((quad + rot) & 7);        // bytes, k-chunk c=0
    int cb1 = 16 * ((quad + 4 + rot) & 7);    // bytes, k-chunk c=1

    __syncthreads();   // buf 0 ready (ds_write visible; cs copy4 drained by vmcnt)

    for (int kt = 0; kt < 32; kt++) {
        int p = kt & 1;
        // (1) issue next tile's global->reg load NOW; lands during compute below
        uintx4 nreg;
        if (kt < 31) {
            int kn = kt + 1;
            nreg = *reinterpret_cast<const uintx4*>(gsrc0 + (size_t)kn * gstep);
            if (w == 4)      async_copy4(&cosP[phBase + kn * 64 + lane], &csB[p ^ 1][lane]);
            else if (w == 5) async_copy4(&sinP[phBase + kn * 64 + lane], &csB[p ^ 1][64 + lane]);
        }

        // (2) compute tile kt from buf p
        // QK^T: S(i,j) C-layout (i=quad*4+r, j=l15 per 16-subtile)
        floatx4 st[4];
#pragma unroll
        for (int jt = 0; jt < 4; jt++) {
            const char* kr = (const char*)&KsB[p][(jt * 16 + l15) * 64];
            short8 kf0 = *reinterpret_cast<const short8*>(kr + cb0);
            short8 kf1 = *reinterpret_cast<const short8*>(kr + cb1);
            floatx4 s = (floatx4){0.f, 0.f, 0.f, 0.f};
            s = __builtin_amdgcn_mfma_f32_16x16x32_bf16(qf[0], kf0, s, 0, 0, 0);
            s = __builtin_amdgcn_mfma_f32_16x16x32_bf16(qf[1], kf1, s, 0, 0, 0);
            st[jt] = s;
        }

        float cjv[4], sjv[4];
#pragma unroll
        for (int jt = 0; jt < 4; jt++) {
            cjv[jt] = csB[p][jt * 16 + l15];
            sjv[jt] = csB[p][64 + jt * 16 + l15];
        }

        // P = exp2(S + coherence) -> packed bf16 in Plb[w] (pi column order).
        unsigned int* pl = reinterpret_cast<unsigned int*>(&Plb[w][0]);
#pragma unroll
        for (int rp = 0; rp < 2; rp++) {
            float2v a0, a1, a2, a3;
            {
                float2v s0 = (float2v){st[0][rp * 2], st[0][rp * 2 + 1]};
                float2v s1 = (float2v){st[1][rp * 2], st[1][rp * 2 + 1]};
                float2v s2 = (float2v){st[2][rp * 2], st[2][rp * 2 + 1]};
                float2v s3 = (float2v){st[3][rp * 2], st[3][rp * 2 + 1]};
                a0 = si2[rp] * sjv[0] + (ci2[rp] * cjv[0] + s0);
                a1 = si2[rp] * sjv[1] + (ci2[rp] * cjv[1] + s1);
                a2 = si2[rp] * sjv[2] + (ci2[rp] * cjv[2] + s2);
                a3 = si2[rp] * sjv[3] + (ci2[rp] * cjv[3] + s3);
            }
            int row = quad * 4 + rp * 2;
            pl[row * 36 + l15]      = pack2_bf16(__builtin_amdgcn_exp2f(a1.x),
                                                 __builtin_amdgcn_exp2f(a0.x));
            pl[row * 36 + 16 + l15] = pack2_bf16(__builtin_amdgcn_exp2f(a3.x),
                                                 __builtin_amdgcn_exp2f(a2.x));
            pl[(row + 1) * 36 + l15]      = pack2_bf16(__builtin_amdgcn_exp2f(a1.y),
                                                       __builtin_amdgcn_exp2f(a0.y));
            pl[(row + 1) * 36 + 16 + l15] = pack2_bf16(__builtin_amdgcn_exp2f(a3.y),
                                                       __builtin_amdgcn_exp2f(a2.y));
        }

        // P A-frags (rows i, pi-ordered k)
        short8 pf[2];
#pragma unroll
        for (int c = 0; c < 2; c++)
            pf[c] = *reinterpret_cast<const short8*>(
                &Plb[w][l15 * 72 + c * 32 + quad * 8]);

        // O += P @ V; l += P @ ones
#pragma unroll
        for (int c = 0; c < 2; c++) {
            int cb = c ? cb1 : cb0;
#pragma unroll
            for (int tt = 0; tt < 4; tt++) {
                const char* vr = (const char*)&VtB[p][(tt * 16 + l15) * 64];
                short8 vf = *reinterpret_cast<const short8*>(vr + cb);
                oacc[tt] = __builtin_amdgcn_mfma_f32_16x16x32_bf16(pf[c], vf, oacc[tt], 0, 0, 0);
            }
            lacc = __builtin_amdgcn_mfma_f32_16x16x32_bf16(pf[c], ones8, lacc, 0, 0, 0);
        }

        // (3) write next tile to the other buffer (vmcnt wait lands here, post-compute)
        if (kt < 31)
            *reinterpret_cast<uintx4*>(ldst[p ^ 1]) = nreg;
        // (4) single barrier: ds_writes visible, cs copy4 drained
        __syncthreads();
    }

    // epilogue: normalize rows by l and write ctx[b][s][h*64+d]
    int b = bh >> 4, h = bh & 15;
    float inv[4];
#pragma unroll
    for (int r = 0; r < 4; r++) inv[r] = 1.0f / lacc[r];
#pragma unroll
    for (int tt = 0; tt < 4; tt++)
#pragma unroll
        for (int r = 0; r < 4; r++) {
            int srow = m0 + quad * 4 + r;
            ctx[((size_t)(b * S_LEN + srow)) * 1024 + h * 64 + tt * 16 + l15] =
                f2bf(oacc[tt][r] * inv[r]);
        }
}

extern "C" void kernel_launch(void* const* d_in, const int* in_sizes, int n_in,
                              void* d_out, int out_size, void* d_ws, size_t ws_size,
                              hipStream_t stream) {
    const float* x     = (const float*)d_in[0];
    const float* Wq    = (const float*)d_in[1];
    const float* bq    = (const float*)d_in[2];
    const float* Wk    = (const float*)d_in[3];
    const float* bk    = (const float*)d_in[4];
    const float* Wv    = (const float*)d_in[5];
    const float* bv    = (const float*)d_in[6];
    const float* Wo    = (const float*)d_in[7];
    const float* bo    = (const float*)d_in[8];
    const float* Wp    = (const float*)d_in[9];
    const float* bp    = (const float*)d_in[10];
    const float* alpha = (const float*)d_in[11];
    float* out = (float*)d_out;

    const size_t MB = 1048576;
    char* ws = (char*)d_ws;
    unsigned short* WT   = (unsigned short*)(ws);             // 3072x1024 bf16
    unsigned short* WoT  = (unsigned short*)(ws + 6 * MB);    // 1024x1024 bf16
    unsigned short* xb   = (unsigned short*)(ws + 8 * MB);    // (B,S,D) bf16
    unsigned short* ctx  = (unsigned short*)(ws + 8 * MB);    // aliases xb
    unsigned short* Qw   = (unsigned short*)(ws + 16 * MB);   // (B,H,S,dk), pre-scaled
    unsigned short* Kw   = (unsigned short*)(ws + 24 * MB);   // (B,H,S,dk)
    unsigned short* VTg  = (unsigned short*)(ws + 32 * MB);   // (B,H,dk,S) pi-interleaved
    float* cosP          = (float*)(ws + 40 * MB);
    float* sinP          = (float*)(ws + 40 * MB + 262144);

    prep_kernel<<<dim3(5120), dim3(256), 0, stream>>>(
        x, Wp, bp, Wq, Wk, Wv, Wo,
        WT, WT + 1048576, WT + 2097152, WoT, cosP, sinP, xb);
    gemm_bt<128><<<dim3(32, 24), dim3(256), 0, stream>>>(
        xb, WT, 3072, 1, bq, bk, bv, Qw, Kw, VTg, (float*)nullptr);
    attn_kernel<<<dim3(256), dim3(1024), 0, stream>>>(
        Qw, Kw, VTg, cosP, sinP, alpha, ctx);
    gemm_bt<64><<<dim3(64, 8), dim3(256), 0, stream>>>(
        ctx, WoT, 1024, 0, bo, bo, bo,
        (unsigned short*)nullptr, (unsigned short*)nullptr,
        (unsigned short*)nullptr, out);
}